// Round 1
// baseline (69.733 us; speedup 1.0000x reference)
//
#include <hip/hip_runtime.h>
#include <math.h>

#define NQ 23
#define IN_DIM 1024

// Apply complex 2x2 gate to qubit q (q in {0,1}) of a 4-amplitude state.
// Index convention: flat idx = b1*2 + b0, qubit q = bit q (matches reference
// reshape(-1, 2, 2**q) stride-2^q convention).
__device__ inline void apply_gate_q(float* re, float* im, int q,
                                    float g00r, float g00i, float g01r, float g01i,
                                    float g10r, float g10i, float g11r, float g11i)
{
    const int stride = 1 << q;
    for (int b = 0; b < 2; ++b) {
        const int i0 = (q == 0) ? (b * 2) : b;
        const int i1 = i0 + stride;
        const float ar = re[i0], ai = im[i0];
        const float br = re[i1], bi = im[i1];
        re[i0] = g00r * ar - g00i * ai + g01r * br - g01i * bi;
        im[i0] = g00r * ai + g00i * ar + g01r * bi + g01i * br;
        re[i1] = g10r * ar - g10i * ai + g11r * br - g11i * bi;
        im[i1] = g10r * ai + g10i * ar + g11r * bi + g11i * br;
    }
}

__global__ __launch_bounds__(1024)
void qnn_kernel(const float* __restrict__ x,
                const float* __restrict__ W,
                const float* __restrict__ qp,
                float* __restrict__ out)
{
    const int t    = threadIdx.x;       // 0..1023
    const int lane = t & 63;
    const int wave = t >> 6;            // 0..15

    __shared__ float partial[NQ][16];
    __shared__ float hsh[2];

    // ---- h = tanh(W @ x): 23 rows, 1024-element dot each ----
    const float xv = x[t];
    #pragma unroll 1
    for (int r = 0; r < NQ; ++r) {
        float v = W[r * IN_DIM + t] * xv;
        // 64-lane wave reduction
        v += __shfl_xor(v, 32, 64);
        v += __shfl_xor(v, 16, 64);
        v += __shfl_xor(v,  8, 64);
        v += __shfl_xor(v,  4, 64);
        v += __shfl_xor(v,  2, 64);
        v += __shfl_xor(v,  1, 64);
        if (lane == 0) partial[r][wave] = v;
    }
    __syncthreads();

    if (t < NQ) {
        float s = 0.f;
        #pragma unroll
        for (int w = 0; w < 16; ++w) s += partial[t][w];
        const float h = tanhf(s);
        out[t] = h;
        if (t < 2) hsh[t] = h;
    }
    __syncthreads();

    // ---- exp_val = <Z_0>: exact 2-qubit (4-amplitude) reduced simulation ----
    // Heisenberg lightcone of Z_0 through the CNOT chains is {q0, q1} only.
    if (t == 0) {
        float re[4] = {1.f, 0.f, 0.f, 0.f};
        float im[4] = {0.f, 0.f, 0.f, 0.f};

        // initial RY(2*h_q)|0> on qubits 0,1  (half-angle = h_q), real gate
        for (int q = 0; q < 2; ++q) {
            const float h = hsh[q];
            const float c = cosf(h), s = sinf(h);
            apply_gate_q(re, im, q,
                         c, 0.f, -s, 0.f,
                         s, 0.f,  c, 0.f);
        }

        // 2 layers: RX, RZ on q0 and q1, then CNOT(control=0 -> target=1)
        for (int layer = 0; layer < 2; ++layer) {
            for (int q = 0; q < 2; ++q) {
                const int idx = layer * NQ * 2 + q * 2;
                // RX(theta): [[c, -i s], [-i s, c]], half-angle theta/2
                {
                    const float th = qp[idx] * 0.5f;
                    const float c = cosf(th), s = sinf(th);
                    apply_gate_q(re, im, q,
                                 c, 0.f, 0.f, -s,
                                 0.f, -s, c, 0.f);
                }
                // RZ(phi): diag(e^{-i phi/2}, e^{+i phi/2})
                {
                    const float ph = qp[idx + 1] * 0.5f;
                    const float c = cosf(ph), s = sinf(ph);
                    apply_gate_q(re, im, q,
                                 c, -s, 0.f, 0.f,
                                 0.f, 0.f, c, s);
                }
            }
            // CNOT(0->1): flip bit1 where bit0==1 -> swap amplitudes 1 <-> 3
            {
                float tr = re[1], ti = im[1];
                re[1] = re[3]; im[1] = im[3];
                re[3] = tr;    im[3] = ti;
            }
        }

        // <Z_0> = sum |amp|^2 * (-1)^{bit0}
        const float expv = (re[0] * re[0] + im[0] * im[0])
                         - (re[1] * re[1] + im[1] * im[1])
                         + (re[2] * re[2] + im[2] * im[2])
                         - (re[3] * re[3] + im[3] * im[3]);
        out[NQ] = expv;
    }
}

extern "C" void kernel_launch(void* const* d_in, const int* in_sizes, int n_in,
                              void* d_out, int out_size, void* d_ws, size_t ws_size,
                              hipStream_t stream)
{
    const float* x  = (const float*)d_in[0];   // (1024,)
    const float* W  = (const float*)d_in[1];   // (23, 1024)
    const float* qp = (const float*)d_in[2];   // (92,)
    float* out = (float*)d_out;                // 23 (h) + 1 (exp_val)

    qnn_kernel<<<1, 1024, 0, stream>>>(x, W, qp, out);
}

// Round 2
// 60.367 us; speedup vs baseline: 1.1552x; 1.1552x over previous
//
#include <hip/hip_runtime.h>
#include <math.h>

#define NQ 23
#define IN_DIM 1024

// Apply complex 2x2 gate to qubit q (q in {0,1}) of a 4-amplitude state.
// flat idx = b1*2 + b0 (qubit q = bit q, matching reference reshape stride-2^q).
__device__ inline void apply_gate_q(float* re, float* im, int q,
                                    float g00r, float g00i, float g01r, float g01i,
                                    float g10r, float g10i, float g11r, float g11i)
{
    const int stride = 1 << q;
    for (int b = 0; b < 2; ++b) {
        const int i0 = (q == 0) ? (b * 2) : b;
        const int i1 = i0 + stride;
        const float ar = re[i0], ai = im[i0];
        const float br = re[i1], bi = im[i1];
        re[i0] = g00r * ar - g00i * ai + g01r * br - g01i * bi;
        im[i0] = g00r * ai + g00i * ar + g01r * bi + g01i * br;
        re[i1] = g10r * ar - g10i * ai + g11r * br - g11i * bi;
        im[i1] = g10r * ai + g10i * ar + g11r * bi + g11i * br;
    }
}

__device__ inline float dot4(float4 a, float4 b)
{
    return a.x * b.x + a.y * b.y + a.z * b.z + a.w * b.w;
}

__device__ inline float wave_reduce(float v)
{
    v += __shfl_xor(v, 32, 64);
    v += __shfl_xor(v, 16, 64);
    v += __shfl_xor(v,  8, 64);
    v += __shfl_xor(v,  4, 64);
    v += __shfl_xor(v,  2, 64);
    v += __shfl_xor(v,  1, 64);
    return v;
}

// Grid: 24 blocks x 256 threads.
// Blocks 0..22: out[b] = tanh(dot(W[b], x))   (one float4 per thread)
// Block 23: recompute h0,h1 redundantly, then exact 2-qubit reduced sim
//           (Heisenberg lightcone of Z_0 through the CNOT chains is {q0,q1}),
//           write out[23] = <Z_0>.
__global__ __launch_bounds__(256)
void qnn_kernel(const float* __restrict__ x,
                const float* __restrict__ W,
                const float* __restrict__ qp,
                float* __restrict__ out)
{
    const int t    = threadIdx.x;   // 0..255
    const int lane = t & 63;
    const int wave = t >> 6;        // 0..3
    const int b    = blockIdx.x;

    __shared__ float partial[4];
    __shared__ float hsh[2];

    const float4* __restrict__ x4 = (const float4*)x;
    const float4* __restrict__ W4 = (const float4*)W;

    const float4 xv = x4[t];

    if (b < NQ) {
        const float4 w = W4[b * 256 + t];
        float v = wave_reduce(dot4(w, xv));
        if (lane == 0) partial[wave] = v;
        __syncthreads();
        if (t == 0)
            out[b] = tanhf(partial[0] + partial[1] + partial[2] + partial[3]);
        return;
    }

    // ---- block 23: h0, h1 then the 4-amplitude circuit ----
    #pragma unroll
    for (int r = 0; r < 2; ++r) {
        const float4 w = W4[r * 256 + t];
        float v = wave_reduce(dot4(w, xv));
        if (lane == 0) partial[wave] = v;
        __syncthreads();
        if (t == 0)
            hsh[r] = tanhf(partial[0] + partial[1] + partial[2] + partial[3]);
        __syncthreads();
    }

    if (t == 0) {
        float re[4] = {1.f, 0.f, 0.f, 0.f};
        float im[4] = {0.f, 0.f, 0.f, 0.f};

        // initial RY(2*h_q)|0> on qubits 0,1 (half-angle = h_q), real gate
        for (int q = 0; q < 2; ++q) {
            const float h = hsh[q];
            const float c = cosf(h), s = sinf(h);
            apply_gate_q(re, im, q,
                         c, 0.f, -s, 0.f,
                         s, 0.f,  c, 0.f);
        }

        // 2 layers: RX, RZ on q0,q1, then CNOT(control=0 -> target=1)
        for (int layer = 0; layer < 2; ++layer) {
            for (int q = 0; q < 2; ++q) {
                const int idx = layer * NQ * 2 + q * 2;
                {   // RX(theta): [[c, -i s], [-i s, c]]
                    const float th = qp[idx] * 0.5f;
                    const float c = cosf(th), s = sinf(th);
                    apply_gate_q(re, im, q,
                                 c, 0.f, 0.f, -s,
                                 0.f, -s, c, 0.f);
                }
                {   // RZ(phi): diag(e^{-i phi/2}, e^{+i phi/2})
                    const float ph = qp[idx + 1] * 0.5f;
                    const float c = cosf(ph), s = sinf(ph);
                    apply_gate_q(re, im, q,
                                 c, -s, 0.f, 0.f,
                                 0.f, 0.f, c, s);
                }
            }
            // CNOT(0->1): swap amplitudes 1 <-> 3
            {
                const float tr = re[1], ti = im[1];
                re[1] = re[3]; im[1] = im[3];
                re[3] = tr;    im[3] = ti;
            }
        }

        // <Z_0> = sum |amp|^2 * (-1)^{bit0}
        const float expv = (re[0] * re[0] + im[0] * im[0])
                         - (re[1] * re[1] + im[1] * im[1])
                         + (re[2] * re[2] + im[2] * im[2])
                         - (re[3] * re[3] + im[3] * im[3]);
        out[NQ] = expv;
    }
}

extern "C" void kernel_launch(void* const* d_in, const int* in_sizes, int n_in,
                              void* d_out, int out_size, void* d_ws, size_t ws_size,
                              hipStream_t stream)
{
    const float* x  = (const float*)d_in[0];   // (1024,)
    const float* W  = (const float*)d_in[1];   // (23, 1024)
    const float* qp = (const float*)d_in[2];   // (92,)
    float* out = (float*)d_out;                // 23 (h) + 1 (exp_val)

    qnn_kernel<<<NQ + 1, 256, 0, stream>>>(x, W, qp, out);
}

// Round 3
// 59.315 us; speedup vs baseline: 1.1756x; 1.0177x over previous
//
#include <hip/hip_runtime.h>
#include <math.h>

#define NQ 23
#define IN_DIM 1024

// Apply complex 2x2 gate to qubit q (q in {0,1}) of a 4-amplitude state.
// flat idx = b1*2 + b0 (qubit q = bit q, matching reference reshape stride-2^q).
__device__ inline void apply_gate_q(float* re, float* im, int q,
                                    float g00r, float g00i, float g01r, float g01i,
                                    float g10r, float g10i, float g11r, float g11i)
{
    const int stride = 1 << q;
    for (int b = 0; b < 2; ++b) {
        const int i0 = (q == 0) ? (b * 2) : b;
        const int i1 = i0 + stride;
        const float ar = re[i0], ai = im[i0];
        const float br = re[i1], bi = im[i1];
        re[i0] = g00r * ar - g00i * ai + g01r * br - g01i * bi;
        im[i0] = g00r * ai + g00i * ar + g01r * bi + g01i * br;
        re[i1] = g10r * ar - g10i * ai + g11r * br - g11i * bi;
        im[i1] = g10r * ai + g10i * ar + g11r * bi + g11i * br;
    }
}

__device__ inline float dot4(float4 a, float4 b)
{
    return a.x * b.x + a.y * b.y + a.z * b.z + a.w * b.w;
}

__device__ inline float wave_reduce(float v)
{
    v += __shfl_xor(v, 32, 64);
    v += __shfl_xor(v, 16, 64);
    v += __shfl_xor(v,  8, 64);
    v += __shfl_xor(v,  4, 64);
    v += __shfl_xor(v,  2, 64);
    v += __shfl_xor(v,  1, 64);
    return v;
}

// One full row dot-product by a single 64-lane wave: thread t accumulates
// 4 float4 chunks (16 elements), then one shuffle reduce. No LDS, no barrier.
__device__ inline float row_dot(const float4* __restrict__ W4,
                                const float4* __restrict__ x4,
                                int row, int t)
{
    const int base = row * 256;           // 256 float4 per row
    float v = dot4(W4[base + t],       x4[t])
            + dot4(W4[base + 64 + t],  x4[64 + t])
            + dot4(W4[base + 128 + t], x4[128 + t])
            + dot4(W4[base + 192 + t], x4[192 + t]);
    return wave_reduce(v);
}

// Grid: 24 blocks x 64 threads (one wave each).
// Blocks 0..22: out[b] = tanh(dot(W[b], x))
// Block 23: recompute h0,h1 redundantly, then the exact 2-qubit reduced sim
//           (Heisenberg lightcone of Z_0 through the CNOT chains is {q0,q1});
//           write out[23] = <Z_0>.
__global__ __launch_bounds__(64)
void qnn_kernel(const float* __restrict__ x,
                const float* __restrict__ W,
                const float* __restrict__ qp,
                float* __restrict__ out)
{
    const int t = threadIdx.x;   // 0..63
    const int b = blockIdx.x;

    const float4* __restrict__ x4 = (const float4*)x;
    const float4* __restrict__ W4 = (const float4*)W;

    if (b < NQ) {
        const float s = row_dot(W4, x4, b, t);
        if (t == 0) out[b] = tanhf(s);
        return;
    }

    // ---- block 23: h0, h1 then the 4-amplitude circuit ----
    const float s0 = row_dot(W4, x4, 0, t);
    const float s1 = row_dot(W4, x4, 1, t);

    if (t == 0) {
        const float h0 = tanhf(s0);
        const float h1 = tanhf(s1);

        float re[4] = {1.f, 0.f, 0.f, 0.f};
        float im[4] = {0.f, 0.f, 0.f, 0.f};

        // initial RY(2*h_q)|0> on qubits 0,1 (half-angle = h_q), real gate
        {
            const float c0 = cosf(h0), sn0 = sinf(h0);
            apply_gate_q(re, im, 0, c0, 0.f, -sn0, 0.f, sn0, 0.f, c0, 0.f);
            const float c1 = cosf(h1), sn1 = sinf(h1);
            apply_gate_q(re, im, 1, c1, 0.f, -sn1, 0.f, sn1, 0.f, c1, 0.f);
        }

        // 2 layers: RX, RZ on q0,q1, then CNOT(control=0 -> target=1)
        for (int layer = 0; layer < 2; ++layer) {
            for (int q = 0; q < 2; ++q) {
                const int idx = layer * NQ * 2 + q * 2;
                {   // RX(theta): [[c, -i s], [-i s, c]]
                    const float th = qp[idx] * 0.5f;
                    const float c = cosf(th), s = sinf(th);
                    apply_gate_q(re, im, q,
                                 c, 0.f, 0.f, -s,
                                 0.f, -s, c, 0.f);
                }
                {   // RZ(phi): diag(e^{-i phi/2}, e^{+i phi/2})
                    const float ph = qp[idx + 1] * 0.5f;
                    const float c = cosf(ph), s = sinf(ph);
                    apply_gate_q(re, im, q,
                                 c, -s, 0.f, 0.f,
                                 0.f, 0.f, c, s);
                }
            }
            // CNOT(0->1): swap amplitudes 1 <-> 3
            {
                const float tr = re[1], ti = im[1];
                re[1] = re[3]; im[1] = im[3];
                re[3] = tr;    im[3] = ti;
            }
        }

        // <Z_0> = sum |amp|^2 * (-1)^{bit0}
        const float expv = (re[0] * re[0] + im[0] * im[0])
                         - (re[1] * re[1] + im[1] * im[1])
                         + (re[2] * re[2] + im[2] * im[2])
                         - (re[3] * re[3] + im[3] * im[3]);
        out[NQ] = expv;
    }
}

extern "C" void kernel_launch(void* const* d_in, const int* in_sizes, int n_in,
                              void* d_out, int out_size, void* d_ws, size_t ws_size,
                              hipStream_t stream)
{
    const float* x  = (const float*)d_in[0];   // (1024,)
    const float* W  = (const float*)d_in[1];   // (23, 1024)
    const float* qp = (const float*)d_in[2];   // (92,)
    float* out = (float*)d_out;                // 23 (h) + 1 (exp_val)

    qnn_kernel<<<NQ + 1, 64, 0, stream>>>(x, W, qp, out);
}